// Round 7
// baseline (463.491 us; speedup 1.0000x reference)
//
#include <hip/hip_runtime.h>
#include <math.h>

// Problem constants (B=2,S=2048,D=768,E=8,F=3072)
#define T_TOK 4096
#define DDIM  768
#define EXP   8
#define FDIM  3072
#define W8CNT ((EXP * FDIM * DDIM) / 8)   // 2359296 8-float units per weight tensor

typedef __bf16 bf16x8 __attribute__((ext_vector_type(8)));
typedef float  f32x4  __attribute__((ext_vector_type(4)));

__device__ __forceinline__ ushort f2bf(float f) {
    union { float f; unsigned u; } v; v.f = f;
    unsigned r = v.u + 0x7fffu + ((v.u >> 16) & 1u);   // RNE
    return (ushort)(r >> 16);
}
__device__ __forceinline__ unsigned pack2(float a, float b) {
    return (unsigned)f2bf(a) | ((unsigned)f2bf(b) << 16);
}

// async global->LDS, 16B per lane; LDS base wave-uniform (HW adds lane*16)
__device__ __forceinline__ void gl_lds16(const void* g, void* l) {
    __builtin_amdgcn_global_load_lds(
        (__attribute__((address_space(1))) void*)(g),
        (__attribute__((address_space(3))) void*)(l), 16, 0, 0);
}

// counted vmem wait (T4)
template <int N> __device__ __forceinline__ void vm_wait() {
    if constexpr (N == 0)      asm volatile("s_waitcnt vmcnt(0)" ::: "memory");
    else if constexpr (N == 4) asm volatile("s_waitcnt vmcnt(4)" ::: "memory");
    else if constexpr (N == 6) asm volatile("s_waitcnt vmcnt(6)" ::: "memory");
    else if constexpr (N == 8) asm volatile("s_waitcnt vmcnt(8)" ::: "memory");
    else                       asm volatile("s_waitcnt vmcnt(0)" ::: "memory");
}
__device__ __forceinline__ void sbar() {
    __builtin_amdgcn_sched_barrier(0);
    __builtin_amdgcn_s_barrier();
    __builtin_amdgcn_sched_barrier(0);
}

// ---------------- router: logits f32, gate+argmax, token lists, x->bf16 ----
__global__ __launch_bounds__(256) void router_kernel(
    const float* __restrict__ x, const float* __restrict__ Wr,
    int* __restrict__ counts, int* __restrict__ tlist,
    float* __restrict__ gates, ushort* __restrict__ xb)
{
    const int lane = threadIdx.x & 63;
    const int wv   = threadIdx.x >> 6;
    const int t    = blockIdx.x * 4 + wv;
    const float4* xr4 = (const float4*)(x + (size_t)t * DDIM);
    float4 xv[3];
#pragma unroll
    for (int j = 0; j < 3; ++j) xv[j] = xr4[lane + 64 * j];
    uint2* xbw = (uint2*)(xb + (size_t)t * DDIM);
#pragma unroll
    for (int j = 0; j < 3; ++j) {
        uint2 p; p.x = pack2(xv[j].x, xv[j].y); p.y = pack2(xv[j].z, xv[j].w);
        xbw[lane + 64 * j] = p;
    }
    float acc[EXP];
#pragma unroll
    for (int e = 0; e < EXP; ++e) {
        const float4* wr4 = (const float4*)(Wr + e * DDIM);
        float a = 0.f;
#pragma unroll
        for (int j = 0; j < 3; ++j) {
            float4 w = wr4[lane + 64 * j];
            a += xv[j].x * w.x + xv[j].y * w.y + xv[j].z * w.z + xv[j].w * w.w;
        }
        acc[e] = a;
    }
#pragma unroll
    for (int off = 32; off > 0; off >>= 1) {
#pragma unroll
        for (int e = 0; e < EXP; ++e) acc[e] += __shfl_xor(acc[e], off);
    }
    if (lane == 0) {
        // complexity bias is uniform over experts -> softmax/argmax invariant
        float m = acc[0]; int am = 0;
#pragma unroll
        for (int e = 1; e < EXP; ++e) if (acc[e] > m) { m = acc[e]; am = e; }
        float s = 0.f;
#pragma unroll
        for (int e = 0; e < EXP; ++e) s += expf(acc[e] - m);
        gates[t] = 1.0f / s;
        int pos = atomicAdd(&counts[am], 1);
        tlist[am * T_TOK + pos] = t;
    }
}

// ------------- W1 convert (coalesced float4/lane) + zero the output -------
__global__ __launch_bounds__(256) void convw1_kernel(
    const float* __restrict__ src, ushort* __restrict__ dst,
    float4* __restrict__ zdst)
{
    const int tid = blockIdx.x * 256 + threadIdx.x;
    const int stride = gridDim.x * 256;
    for (int i = tid; i < W8CNT * 2; i += stride) {
        float4 v = ((const float4*)src)[i];
        uint2 p; p.x = pack2(v.x, v.y); p.y = pack2(v.z, v.w);
        ((uint2*)dst)[i] = p;
    }
    const float4 z = {0.f, 0.f, 0.f, 0.f};
    for (int i = tid; i < (T_TOK * DDIM) / 4; i += stride) zdst[i] = z;
}

// ---------------- standalone convert (fallback path) -----------------------
__global__ __launch_bounds__(256) void convert_kernel(
    const float* __restrict__ src, ushort* __restrict__ dst)
{
    const int tid = blockIdx.x * 256 + threadIdx.x;
    const int stride = gridDim.x * 256;
    for (int i = tid; i < W8CNT * 2; i += stride) {
        float4 v = ((const float4*)src)[i];
        uint2 p; p.x = pack2(v.x, v.y); p.y = pack2(v.z, v.w);
        ((uint2*)dst)[i] = p;
    }
}

// -------- grouped GEMM, m201 geometry: 512 thr, 8 waves, wave=128x64 -------
// block tile BM(=256) x BN(=256), BK=64, counted-vmcnt dbuf, swizzled LDS
// MODE 1: GELU -> H bf16 (z==EXP slice converts W2). MODE 2: atomic out, s=z>>3
template <int BM, int BN, int NTOT, int KSTRIDE, int KLEN, int MODE>
__global__ __launch_bounds__(512, 1) void moe_gemm(
    const ushort* __restrict__ A, const ushort* __restrict__ W,
    ushort* __restrict__ H, float* __restrict__ Out,
    const int* __restrict__ counts, const int* __restrict__ tlist,
    const float* __restrict__ gates,
    const float* __restrict__ csrc, ushort* __restrict__ cdst)
{
    constexpr int BK  = 64;
    constexpr int ACH = BM / 8;               // A chunks (1 KB = 8 rows x 128B)
    constexpr int NCH = (BM + BN) / 8;
    constexpr int CPW = NCH / 8;              // chunks per wave (8)
    constexpr int HT  = (BM + BN) * 128;      // bytes per LDS buffer
    constexpr int MR  = 8, NR = 4;            // wave tile 128x64
    constexpr int NT  = KLEN / BK;

    if (MODE == 1 && blockIdx.z == EXP) {     // fused W2 convert slice
        const int idx0 = (blockIdx.y * gridDim.x + blockIdx.x) * 512 + threadIdx.x;
        const int stride = gridDim.x * gridDim.y * 512;
        for (int i = idx0; i < W8CNT * 2; i += stride) {
            float4 v = ((const float4*)csrc)[i];
            uint2 p; p.x = pack2(v.x, v.y); p.y = pack2(v.z, v.w);
            ((uint2*)cdst)[i] = p;
        }
        return;
    }
    const int e  = blockIdx.z & (EXP - 1);
    const int s  = (MODE == 2) ? (blockIdx.z >> 3) : 0;
    const int Ne = counts[e];
    const int m0 = blockIdx.y * BM;
    if (m0 >= Ne) return;
    const int n0 = blockIdx.x * BN;

    __shared__ __align__(16) char S[2 * HT];  // 128 KB
    char* Sb0 = S;
    char* Sb1 = S + HT;

    const int tid = threadIdx.x, lane = tid & 63, wv = tid >> 6;
    const int* tl = tlist + e * T_TOK;

    // per-lane global pointers; source pre-swizzled (gl_lds writes linearly, #21)
    const int rl = lane >> 3;                 // row within 8-row chunk
    const int sl = (lane & 7) ^ rl;           // swizzled 16B slot
    const ushort* bp[CPW];
#pragma unroll
    for (int i = 0; i < CPW; ++i) {
        const int c = wv * CPW + i;
        if (c < ACH) {
            int slot = m0 + c * 8 + rl;
            if (slot > Ne - 1) slot = Ne - 1;
            bp[i] = A + (size_t)tl[slot] * KSTRIDE + s * KLEN + sl * 8;
        } else {
            const int r = (c - ACH) * 8 + rl;
            bp[i] = W + ((size_t)e * NTOT + n0 + r) * KSTRIDE + s * KLEN + sl * 8;
        }
    }

    f32x4 acc[MR][NR];
#pragma unroll
    for (int m = 0; m < MR; ++m)
#pragma unroll
        for (int n = 0; n < NR; ++n) acc[m][n] = (f32x4)0.f;

    const int wrow = (wv >> 2) * 128;         // 2 wave-rows x 4 wave-cols
    const int wcol = (wv & 3) * 64;

#define STAGE(T, BUF)                                                   \
    {                                                                   \
        _Pragma("unroll")                                               \
        for (int i = 0; i < CPW; ++i)                                   \
            gl_lds16(bp[i] + (T) * BK, (BUF) + (wv * CPW + i) * 1024);  \
    }

    STAGE(0, Sb0);
    STAGE(1, Sb1);

    for (int t = 0; t < NT; ++t) {
        char* curB = (t & 1) ? Sb1 : Sb0;
        if (t + 1 < NT) vm_wait<CPW>();       // tile t landed, t+1 in flight
        else            vm_wait<0>();         // tail: drain (round-5 race fix)
        sbar();
#pragma unroll
        for (int ks = 0; ks < 2; ++ks) {
            const int kb = ks * 64 + (lane >> 4) * 16;
            bf16x8 af[MR], bfr[NR];
#pragma unroll
            for (int m = 0; m < MR; ++m) {
                const int r = wrow + m * 16 + (lane & 15);
                const int b = (r * 128 + kb) ^ ((r & 7) << 4);
                af[m] = *(const bf16x8*)(curB + b);
            }
#pragma unroll
            for (int n = 0; n < NR; ++n) {
                const int r = wcol + n * 16 + (lane & 15);
                const int b = (r * 128 + kb) ^ ((r & 7) << 4);
                bfr[n] = *(const bf16x8*)(curB + BM * 128 + b);
            }
#pragma unroll
            for (int m = 0; m < MR; ++m)
#pragma unroll
                for (int n = 0; n < NR; ++n)
                    acc[m][n] = __builtin_amdgcn_mfma_f32_16x16x32_bf16(
                        af[m], bfr[n], acc[m][n], 0, 0, 0);
        }
        sbar();                               // all waves done reading curB
        if (t + 2 < NT) STAGE(t + 2, curB);
    }
#undef STAGE

    // epilogue: C frag row=(lane>>4)*4+j, col=lane&15  [m89 layout]
    const int lr4 = (lane >> 4) * 4, lc = lane & 15;
#pragma unroll
    for (int m = 0; m < MR; ++m) {
        const int rbase = wrow + m * 16 + lr4;
#pragma unroll
        for (int j = 0; j < 4; ++j) {
            const int slot = m0 + rbase + j;
            if (slot >= Ne) continue;
            const int t = tl[slot];
            const float g = (MODE == 2) ? gates[t] : 0.f;
#pragma unroll
            for (int n = 0; n < NR; ++n) {
                float v = acc[m][n][j];
                const int c = n0 + wcol + n * 16 + lc;
                if (MODE == 1) {
                    float gv = 0.5f * v * (1.0f + erff(v * 0.70710678118654752f));
                    H[(size_t)t * NTOT + c] = f2bf(gv);
                } else {
                    unsafeAtomicAdd(&Out[(size_t)t * NTOT + c], v * g);
                }
            }
        }
    }
}

// ---------------- finalize: lb_loss, counts, avg gate, active --------------
__global__ __launch_bounds__(256) void finalize_kernel(
    const float* __restrict__ gates, const int* __restrict__ counts,
    float* __restrict__ tail)
{
    __shared__ float red[256];
    float s = 0.f;
    for (int i = threadIdx.x; i < T_TOK; i += 256) s += gates[i];
    red[threadIdx.x] = s;
    __syncthreads();
    for (int off = 128; off > 0; off >>= 1) {
        if (threadIdx.x < off) red[threadIdx.x] += red[threadIdx.x + off];
        __syncthreads();
    }
    if (threadIdx.x == 0) {
        float lb = 0.f; int active = 0;
#pragma unroll
        for (int e = 0; e < EXP; ++e) {
            float c = (float)counts[e];
            float d = c - 512.0f;
            lb += d * d;
            active += (counts[e] > 0) ? 1 : 0;
        }
        tail[0] = lb * (0.01f / 8.0f);
#pragma unroll
        for (int e = 0; e < EXP; ++e) tail[1 + e] = (float)counts[e];
        tail[9]  = red[0] / (float)T_TOK;
        tail[10] = (float)active;
    }
}

// ---------------- launch ---------------------------------------------------
extern "C" void kernel_launch(void* const* d_in, const int* in_sizes, int n_in,
                              void* d_out, int out_size, void* d_ws, size_t ws_size,
                              hipStream_t stream)
{
    const float* x  = (const float*)d_in[0];
    const float* Wr = (const float*)d_in[2];
    const float* W1 = (const float*)d_in[5];
    const float* W2 = (const float*)d_in[6];
    float* out = (float*)d_out;

    char* ws = (char*)d_ws;
    int*    counts = (int*)ws;                       // 256 B
    int*    tlist  = (int*)(ws + 256);               // 128 KiB
    float*  gates  = (float*)(ws + 131328);          // 16 KiB
    ushort* xb     = (ushort*)(ws + 147712);         // 6.29 MB
    ushort* h      = (ushort*)(ws + 6439168);        // 25.2 MB
    ushort* w1b    = (ushort*)(ws + 31604992);       // 37.75 MB
    const size_t OFF_W2B = 69353728ull;
    const bool fuse = ws_size >= OFF_W2B + 37748736ull;
    ushort* w2b = fuse ? (ushort*)(ws + OFF_W2B) : w1b;

    hipMemsetAsync(counts, 0, 256, stream);
    router_kernel<<<dim3(T_TOK / 4), dim3(256), 0, stream>>>(
        x, Wr, counts, tlist, gates, xb);
    convw1_kernel<<<dim3(4096), dim3(256), 0, stream>>>(W1, w1b, (float4*)out);

    // GEMM1: 256x256 tile, K=768 (NT=12); z=8 slice converts W2 (overlapped)
    if (fuse) {
        moe_gemm<256, 256, FDIM, DDIM, DDIM, 1>
            <<<dim3(FDIM / 256, T_TOK / 256, EXP + 1), dim3(512), 0, stream>>>(
            xb, w1b, h, nullptr, counts, tlist, gates, W2, w2b);
    } else {
        moe_gemm<256, 256, FDIM, DDIM, DDIM, 1>
            <<<dim3(FDIM / 256, T_TOK / 256, EXP), dim3(512), 0, stream>>>(
            xb, w1b, h, nullptr, counts, tlist, gates, nullptr, nullptr);
        convert_kernel<<<dim3(4096), dim3(256), 0, stream>>>(W2, w2b);
    }

    // GEMM2: 256x256 tile, split-K=4 (KLEN=768, NT=12), atomic f32 epilogue
    moe_gemm<256, 256, DDIM, FDIM, FDIM / 4, 2>
        <<<dim3(DDIM / 256, T_TOK / 256, EXP * 4), dim3(512), 0, stream>>>(
        h, w2b, nullptr, out, counts, tlist, gates, nullptr, nullptr);

    finalize_kernel<<<dim3(1), dim3(256), 0, stream>>>(gates, counts, out + (size_t)T_TOK * DDIM);
}

// Round 8
// 449.296 us; speedup vs baseline: 1.0316x; 1.0316x over previous
//
#include <hip/hip_runtime.h>
#include <math.h>

// Problem constants (B=2,S=2048,D=768,E=8,F=3072)
#define T_TOK 4096
#define DDIM  768
#define EXP   8
#define FDIM  3072
#define W8CNT ((EXP * FDIM * DDIM) / 8)   // 2359296 8-float units per weight tensor
#define N4CNT (W8CNT * 2)                 // 4718592 float4 units per weight tensor

typedef __bf16 bf16x8 __attribute__((ext_vector_type(8)));
typedef float  f32x4  __attribute__((ext_vector_type(4)));

__device__ __forceinline__ ushort f2bf(float f) {
    union { float f; unsigned u; } v; v.f = f;
    unsigned r = v.u + 0x7fffu + ((v.u >> 16) & 1u);   // RNE
    return (ushort)(r >> 16);
}
__device__ __forceinline__ unsigned pack2(float a, float b) {
    return (unsigned)f2bf(a) | ((unsigned)f2bf(b) << 16);
}

// 8-deep batched f32->bf16 convert: 8 loads IN FLIGHT, one wait, 8 stores.
// (Non-unrolled load->store loops serialize on in-order vmcnt retirement:
//  round-7 evidence = streaming dispatches stuck at ~0.9-1.1 TB/s.)
__device__ __forceinline__ void conv8(const float4* __restrict__ s,
                                      uint2* __restrict__ d,
                                      int base, int stride) {
    float4 v[8];
#pragma unroll
    for (int j = 0; j < 8; ++j) v[j] = s[base + j * stride];
    uint2 p[8];
#pragma unroll
    for (int j = 0; j < 8; ++j) {
        p[j].x = pack2(v[j].x, v[j].y);
        p[j].y = pack2(v[j].z, v[j].w);
    }
#pragma unroll
    for (int j = 0; j < 8; ++j) d[base + j * stride] = p[j];
}

// async global->LDS, 16B per lane; LDS base wave-uniform (HW adds lane*16)
__device__ __forceinline__ void gl_lds16(const void* g, void* l) {
    __builtin_amdgcn_global_load_lds(
        (__attribute__((address_space(1))) void*)(g),
        (__attribute__((address_space(3))) void*)(l), 16, 0, 0);
}

// counted vmem wait (T4)
template <int N> __device__ __forceinline__ void vm_wait() {
    if constexpr (N == 0)      asm volatile("s_waitcnt vmcnt(0)" ::: "memory");
    else if constexpr (N == 4) asm volatile("s_waitcnt vmcnt(4)" ::: "memory");
    else if constexpr (N == 6) asm volatile("s_waitcnt vmcnt(6)" ::: "memory");
    else if constexpr (N == 8) asm volatile("s_waitcnt vmcnt(8)" ::: "memory");
    else                       asm volatile("s_waitcnt vmcnt(0)" ::: "memory");
}
__device__ __forceinline__ void sbar() {
    __builtin_amdgcn_sched_barrier(0);
    __builtin_amdgcn_s_barrier();
    __builtin_amdgcn_sched_barrier(0);
}

// ---------------- router: logits f32, gate+argmax, token lists, x->bf16 ----
__global__ __launch_bounds__(256) void router_kernel(
    const float* __restrict__ x, const float* __restrict__ Wr,
    int* __restrict__ counts, int* __restrict__ tlist,
    float* __restrict__ gates, ushort* __restrict__ xb)
{
    const int lane = threadIdx.x & 63;
    const int wv   = threadIdx.x >> 6;
    const int t    = blockIdx.x * 4 + wv;
    const float4* xr4 = (const float4*)(x + (size_t)t * DDIM);
    float4 xv[3];
#pragma unroll
    for (int j = 0; j < 3; ++j) xv[j] = xr4[lane + 64 * j];
    uint2* xbw = (uint2*)(xb + (size_t)t * DDIM);
#pragma unroll
    for (int j = 0; j < 3; ++j) {
        uint2 p; p.x = pack2(xv[j].x, xv[j].y); p.y = pack2(xv[j].z, xv[j].w);
        xbw[lane + 64 * j] = p;
    }
    float acc[EXP];
#pragma unroll
    for (int e = 0; e < EXP; ++e) {
        const float4* wr4 = (const float4*)(Wr + e * DDIM);
        float a = 0.f;
#pragma unroll
        for (int j = 0; j < 3; ++j) {
            float4 w = wr4[lane + 64 * j];
            a += xv[j].x * w.x + xv[j].y * w.y + xv[j].z * w.z + xv[j].w * w.w;
        }
        acc[e] = a;
    }
#pragma unroll
    for (int off = 32; off > 0; off >>= 1) {
#pragma unroll
        for (int e = 0; e < EXP; ++e) acc[e] += __shfl_xor(acc[e], off);
    }
    if (lane == 0) {
        // complexity bias is uniform over experts -> softmax/argmax invariant
        float m = acc[0]; int am = 0;
#pragma unroll
        for (int e = 1; e < EXP; ++e) if (acc[e] > m) { m = acc[e]; am = e; }
        float s = 0.f;
#pragma unroll
        for (int e = 0; e < EXP; ++e) s += expf(acc[e] - m);
        gates[t] = 1.0f / s;
        int pos = atomicAdd(&counts[am], 1);
        tlist[am * T_TOK + pos] = t;
    }
}

// ------- W1 convert: 1152 blocks x 512 thr, exactly 8 float4/thread -------
// 589824 threads * 8 = 4718592 = N4CNT. Also zeroes the f32 output buffer.
__global__ __launch_bounds__(512) void convw1_kernel(
    const float* __restrict__ src, ushort* __restrict__ dst,
    float4* __restrict__ zdst)
{
    const int tid = blockIdx.x * 512 + threadIdx.x;   // 0..589823
    conv8((const float4*)src, (uint2*)dst, tid, 589824);
    const float4 z = {0.f, 0.f, 0.f, 0.f};
    for (int i = tid; i < (T_TOK * DDIM) / 4; i += 589824) zdst[i] = z;  // stores only: no stall
}

// ---------------- standalone W2 convert (fallback path) --------------------
__global__ __launch_bounds__(512) void convert_kernel(
    const float* __restrict__ src, ushort* __restrict__ dst)
{
    const int tid = blockIdx.x * 512 + threadIdx.x;
    conv8((const float4*)src, (uint2*)dst, tid, 589824);
}

// -------- grouped GEMM, 512 thr, 8 waves, wave=128x64, BK=64 ---------------
// counted-vmcnt double buffer + both-sides swizzle (conflicts measured 0)
// MODE 1: GELU -> H bf16 (z==EXP slice = batched W2 convert). MODE 2: atomic out
template <int BM, int BN, int NTOT, int KSTRIDE, int KLEN, int MODE>
__global__ __launch_bounds__(512, 1) void moe_gemm(
    const ushort* __restrict__ A, const ushort* __restrict__ W,
    ushort* __restrict__ H, float* __restrict__ Out,
    const int* __restrict__ counts, const int* __restrict__ tlist,
    const float* __restrict__ gates,
    const float* __restrict__ csrc, ushort* __restrict__ cdst)
{
    constexpr int BK  = 64;
    constexpr int ACH = BM / 8;               // A chunks (1 KB = 8 rows x 128B)
    constexpr int NCH = (BM + BN) / 8;
    constexpr int CPW = NCH / 8;              // chunks per wave (8)
    constexpr int HT  = (BM + BN) * 128;      // bytes per LDS buffer
    constexpr int MR  = 8, NR = 4;            // wave tile 128x64
    constexpr int NT  = KLEN / BK;

    if (MODE == 1 && blockIdx.z == EXP) {     // fused W2 convert slice (batched)
        // 192 blocks x 512 thr = 98304 threads; 48 elems each = 6 x conv8
        const int flat = (blockIdx.y * gridDim.x + blockIdx.x) * 512 + threadIdx.x;
#pragma unroll
        for (int o = 0; o < 6; ++o)
            conv8((const float4*)csrc, (uint2*)cdst, flat + o * 786432, 98304);
        return;
    }
    const int e  = blockIdx.z & (EXP - 1);
    const int s  = (MODE == 2) ? (blockIdx.z >> 3) : 0;
    const int Ne = counts[e];
    const int m0 = blockIdx.y * BM;
    if (m0 >= Ne) return;
    const int n0 = blockIdx.x * BN;

    __shared__ __align__(16) char S[2 * HT];  // 128 KB
    char* Sb0 = S;
    char* Sb1 = S + HT;

    const int tid = threadIdx.x, lane = tid & 63, wv = tid >> 6;
    const int* tl = tlist + e * T_TOK;

    // per-lane global pointers; source pre-swizzled (gl_lds writes linearly, #21)
    const int rl = lane >> 3;                 // row within 8-row chunk
    const int sl = (lane & 7) ^ rl;           // swizzled 16B slot
    const ushort* bp[CPW];
#pragma unroll
    for (int i = 0; i < CPW; ++i) {
        const int c = wv * CPW + i;
        if (c < ACH) {
            int slot = m0 + c * 8 + rl;
            if (slot > Ne - 1) slot = Ne - 1;
            bp[i] = A + (size_t)tl[slot] * KSTRIDE + s * KLEN + sl * 8;
        } else {
            const int r = (c - ACH) * 8 + rl;
            bp[i] = W + ((size_t)e * NTOT + n0 + r) * KSTRIDE + s * KLEN + sl * 8;
        }
    }

    f32x4 acc[MR][NR];
#pragma unroll
    for (int m = 0; m < MR; ++m)
#pragma unroll
        for (int n = 0; n < NR; ++n) acc[m][n] = (f32x4)0.f;

    const int wrow = (wv >> 2) * 128;         // 2 wave-rows x 4 wave-cols
    const int wcol = (wv & 3) * 64;

#define STAGE(T, BUF)                                                   \
    {                                                                   \
        _Pragma("unroll")                                               \
        for (int i = 0; i < CPW; ++i)                                   \
            gl_lds16(bp[i] + (T) * BK, (BUF) + (wv * CPW + i) * 1024);  \
    }

    STAGE(0, Sb0);
    STAGE(1, Sb1);

    for (int t = 0; t < NT; ++t) {
        char* curB = (t & 1) ? Sb1 : Sb0;
        if (t + 1 < NT) vm_wait<CPW>();       // tile t landed, t+1 in flight
        else            vm_wait<0>();         // tail: drain
        sbar();
#pragma unroll
        for (int ks = 0; ks < 2; ++ks) {
            const int kb = ks * 64 + (lane >> 4) * 16;
            bf16x8 af[MR], bfr[NR];
#pragma unroll
            for (int m = 0; m < MR; ++m) {
                const int r = wrow + m * 16 + (lane & 15);
                const int b = (r * 128 + kb) ^ ((r & 7) << 4);
                af[m] = *(const bf16x8*)(curB + b);
            }
#pragma unroll
            for (int n = 0; n < NR; ++n) {
                const int r = wcol + n * 16 + (lane & 15);
                const int b = (r * 128 + kb) ^ ((r & 7) << 4);
                bfr[n] = *(const bf16x8*)(curB + BM * 128 + b);
            }
#pragma unroll
            for (int m = 0; m < MR; ++m)
#pragma unroll
                for (int n = 0; n < NR; ++n)
                    acc[m][n] = __builtin_amdgcn_mfma_f32_16x16x32_bf16(
                        af[m], bfr[n], acc[m][n], 0, 0, 0);
        }
        sbar();                               // all waves done reading curB
        if (t + 2 < NT) STAGE(t + 2, curB);
    }
#undef STAGE

    // epilogue: C frag row=(lane>>4)*4+j, col=lane&15  [m89 layout]
    const int lr4 = (lane >> 4) * 4, lc = lane & 15;
#pragma unroll
    for (int m = 0; m < MR; ++m) {
        const int rbase = wrow + m * 16 + lr4;
#pragma unroll
        for (int j = 0; j < 4; ++j) {
            const int slot = m0 + rbase + j;
            if (slot >= Ne) continue;
            const int t = tl[slot];
            const float g = (MODE == 2) ? gates[t] : 0.f;
#pragma unroll
            for (int n = 0; n < NR; ++n) {
                float v = acc[m][n][j];
                const int c = n0 + wcol + n * 16 + lc;
                if (MODE == 1) {
                    float gv = 0.5f * v * (1.0f + erff(v * 0.70710678118654752f));
                    H[(size_t)t * NTOT + c] = f2bf(gv);
                } else {
                    unsafeAtomicAdd(&Out[(size_t)t * NTOT + c], v * g);
                }
            }
        }
    }
}

// ---------------- finalize: lb_loss, counts, avg gate, active --------------
__global__ __launch_bounds__(256) void finalize_kernel(
    const float* __restrict__ gates, const int* __restrict__ counts,
    float* __restrict__ tail)
{
    __shared__ float red[256];
    float s = 0.f;
    for (int i = threadIdx.x; i < T_TOK; i += 256) s += gates[i];
    red[threadIdx.x] = s;
    __syncthreads();
    for (int off = 128; off > 0; off >>= 1) {
        if (threadIdx.x < off) red[threadIdx.x] += red[threadIdx.x + off];
        __syncthreads();
    }
    if (threadIdx.x == 0) {
        float lb = 0.f; int active = 0;
#pragma unroll
        for (int e = 0; e < EXP; ++e) {
            float c = (float)counts[e];
            float d = c - 512.0f;
            lb += d * d;
            active += (counts[e] > 0) ? 1 : 0;
        }
        tail[0] = lb * (0.01f / 8.0f);
#pragma unroll
        for (int e = 0; e < EXP; ++e) tail[1 + e] = (float)counts[e];
        tail[9]  = red[0] / (float)T_TOK;
        tail[10] = (float)active;
    }
}

// ---------------- launch ---------------------------------------------------
extern "C" void kernel_launch(void* const* d_in, const int* in_sizes, int n_in,
                              void* d_out, int out_size, void* d_ws, size_t ws_size,
                              hipStream_t stream)
{
    const float* x  = (const float*)d_in[0];
    const float* Wr = (const float*)d_in[2];
    const float* W1 = (const float*)d_in[5];
    const float* W2 = (const float*)d_in[6];
    float* out = (float*)d_out;

    char* ws = (char*)d_ws;
    int*    counts = (int*)ws;                       // 256 B
    int*    tlist  = (int*)(ws + 256);               // 128 KiB
    float*  gates  = (float*)(ws + 131328);          // 16 KiB
    ushort* xb     = (ushort*)(ws + 147712);         // 6.29 MB
    ushort* h      = (ushort*)(ws + 6439168);        // 25.2 MB
    ushort* w1b    = (ushort*)(ws + 31604992);       // 37.75 MB
    const size_t OFF_W2B = 69353728ull;
    const bool fuse = ws_size >= OFF_W2B + 37748736ull;
    ushort* w2b = fuse ? (ushort*)(ws + OFF_W2B) : w1b;

    hipMemsetAsync(counts, 0, 256, stream);
    router_kernel<<<dim3(T_TOK / 4), dim3(256), 0, stream>>>(
        x, Wr, counts, tlist, gates, xb);
    convw1_kernel<<<dim3(1152), dim3(512), 0, stream>>>(W1, w1b, (float4*)out);

    // GEMM1: 256x256 tile, K=768 (NT=12); z=8 slice = batched W2 convert
    if (fuse) {
        moe_gemm<256, 256, FDIM, DDIM, DDIM, 1>
            <<<dim3(FDIM / 256, T_TOK / 256, EXP + 1), dim3(512), 0, stream>>>(
            xb, w1b, h, nullptr, counts, tlist, gates, W2, w2b);
    } else {
        moe_gemm<256, 256, FDIM, DDIM, DDIM, 1>
            <<<dim3(FDIM / 256, T_TOK / 256, EXP), dim3(512), 0, stream>>>(
            xb, w1b, h, nullptr, counts, tlist, gates, nullptr, nullptr);
        convert_kernel<<<dim3(1152), dim3(512), 0, stream>>>(W2, w2b);
    }

    // GEMM2: 256x256 tile, split-K=4 (KLEN=768, NT=12), atomic f32 epilogue
    moe_gemm<256, 256, DDIM, FDIM, FDIM / 4, 2>
        <<<dim3(DDIM / 256, T_TOK / 256, EXP * 4), dim3(512), 0, stream>>>(
        h, w2b, nullptr, out, counts, tlist, gates, nullptr, nullptr);

    finalize_kernel<<<dim3(1), dim3(256), 0, stream>>>(gates, counts, out + (size_t)T_TOK * DDIM);
}

// Round 9
// 361.239 us; speedup vs baseline: 1.2831x; 1.2438x over previous
//
#include <hip/hip_runtime.h>
#include <math.h>

// Problem constants (B=2,S=2048,D=768,E=8,F=3072)
#define T_TOK 4096
#define DDIM  768
#define EXP   8
#define FDIM  3072
#define N4CNT ((EXP * FDIM * DDIM) / 4)   // 4718592 float4 units per weight tensor

typedef __bf16 bf16x8 __attribute__((ext_vector_type(8)));
typedef float  f32x4  __attribute__((ext_vector_type(4)));

__device__ __forceinline__ ushort f2bf(float f) {
    union { float f; unsigned u; } v; v.f = f;
    unsigned r = v.u + 0x7fffu + ((v.u >> 16) & 1u);   // RNE
    return (ushort)(r >> 16);
}
__device__ __forceinline__ unsigned pack2(float a, float b) {
    return (unsigned)f2bf(a) | ((unsigned)f2bf(b) << 16);
}

// 8-deep batched f32->bf16 convert: 8 loads in flight, one wait, 8 stores
__device__ __forceinline__ void conv8(const float4* __restrict__ s,
                                      uint2* __restrict__ d,
                                      int base, int stride) {
    float4 v[8];
#pragma unroll
    for (int j = 0; j < 8; ++j) v[j] = s[base + j * stride];
    uint2 p[8];
#pragma unroll
    for (int j = 0; j < 8; ++j) {
        p[j].x = pack2(v[j].x, v[j].y);
        p[j].y = pack2(v[j].z, v[j].w);
    }
#pragma unroll
    for (int j = 0; j < 8; ++j) d[base + j * stride] = p[j];
}

// async global->LDS, 16B per lane; LDS base wave-uniform (HW adds lane*16)
__device__ __forceinline__ void gl_lds16(const void* g, void* l) {
    __builtin_amdgcn_global_load_lds(
        (__attribute__((address_space(1))) void*)(g),
        (__attribute__((address_space(3))) void*)(l), 16, 0, 0);
}

// counted vmem wait (T4)
template <int N> __device__ __forceinline__ void vm_wait() {
    if constexpr (N == 4)      asm volatile("s_waitcnt vmcnt(4)" ::: "memory");
    else if constexpr (N == 6) asm volatile("s_waitcnt vmcnt(6)" ::: "memory");
    else if constexpr (N == 8) asm volatile("s_waitcnt vmcnt(8)" ::: "memory");
    else                       asm volatile("s_waitcnt vmcnt(0)" ::: "memory");
}
__device__ __forceinline__ void sbar() {
    __builtin_amdgcn_sched_barrier(0);
    __builtin_amdgcn_s_barrier();
    __builtin_amdgcn_sched_barrier(0);
}

// ---------------- router: logits f32, gate+argmax, token lists, x->bf16 ----
__global__ __launch_bounds__(256) void router_kernel(
    const float* __restrict__ x, const float* __restrict__ Wr,
    int* __restrict__ counts, int* __restrict__ tlist,
    float* __restrict__ gates, ushort* __restrict__ xb)
{
    const int lane = threadIdx.x & 63;
    const int wv   = threadIdx.x >> 6;
    const int t    = blockIdx.x * 4 + wv;
    const float4* xr4 = (const float4*)(x + (size_t)t * DDIM);
    float4 xv[3];
#pragma unroll
    for (int j = 0; j < 3; ++j) xv[j] = xr4[lane + 64 * j];
    uint2* xbw = (uint2*)(xb + (size_t)t * DDIM);
#pragma unroll
    for (int j = 0; j < 3; ++j) {
        uint2 p; p.x = pack2(xv[j].x, xv[j].y); p.y = pack2(xv[j].z, xv[j].w);
        xbw[lane + 64 * j] = p;
    }
    float acc[EXP];
#pragma unroll
    for (int e = 0; e < EXP; ++e) {
        const float4* wr4 = (const float4*)(Wr + e * DDIM);
        float a = 0.f;
#pragma unroll
        for (int j = 0; j < 3; ++j) {
            float4 w = wr4[lane + 64 * j];
            a += xv[j].x * w.x + xv[j].y * w.y + xv[j].z * w.z + xv[j].w * w.w;
        }
        acc[e] = a;
    }
#pragma unroll
    for (int off = 32; off > 0; off >>= 1) {
#pragma unroll
        for (int e = 0; e < EXP; ++e) acc[e] += __shfl_xor(acc[e], off);
    }
    if (lane == 0) {
        // complexity bias is uniform over experts -> softmax/argmax invariant
        float m = acc[0]; int am = 0;
#pragma unroll
        for (int e = 1; e < EXP; ++e) if (acc[e] > m) { m = acc[e]; am = e; }
        float s = 0.f;
#pragma unroll
        for (int e = 0; e < EXP; ++e) s += expf(acc[e] - m);
        gates[t] = 1.0f / s;
        int pos = atomicAdd(&counts[am], 1);
        tlist[am * T_TOK + pos] = t;
    }
}

// --- convert BOTH weights: 2304 blocks x 256 thr, 8 float4/thread each ----
__global__ __launch_bounds__(256) void convboth_kernel(
    const float* __restrict__ w1, ushort* __restrict__ d1,
    const float* __restrict__ w2, ushort* __restrict__ d2)
{
    const int tid = blockIdx.x * 256 + threadIdx.x;   // 0..589823
    conv8((const float4*)w1, (uint2*)d1, tid, 589824);
    conv8((const float4*)w2, (uint2*)d2, tid, 589824);
}

// ---------------- single convert (fallback when ws too small) --------------
__global__ __launch_bounds__(256) void convone_kernel(
    const float* __restrict__ src, ushort* __restrict__ dst)
{
    const int tid = blockIdx.x * 256 + threadIdx.x;
    conv8((const float4*)src, (uint2*)dst, tid, 589824);
}

// -------- grouped GEMM: 256 thr, 4 waves (2x2), BK=64, counted-vmcnt -------
// C[slot,n] = sum_k A[tl[slot],k] * W[e,n0+n,k];  no split-K, no atomics
// MODE 1: GELU -> H bf16.  MODE 2: *gate -> Out f32 (plain store)
template <int BM, int BN, int NTOT, int KSTRIDE, int MODE>
__global__ __launch_bounds__(256, 2) void moe_gemm(
    const ushort* __restrict__ A, const ushort* __restrict__ W,
    ushort* __restrict__ H, float* __restrict__ Out,
    const int* __restrict__ counts, const int* __restrict__ tlist,
    const float* __restrict__ gates)
{
    constexpr int BK  = 64;
    constexpr int ACH = BM / 8;               // A chunks (1 KB = 8 rows x 128B)
    constexpr int NCH = (BM + BN) / 8;
    constexpr int CPW = NCH / 4;              // chunks per wave (GEMM1:8, GEMM2:6)
    constexpr int HT  = (BM + BN) * 128;      // bytes per LDS buffer
    constexpr int MR  = BM / 32, NR = BN / 32;
    constexpr int NT  = KSTRIDE / BK;

    const int e  = blockIdx.z;
    const int Ne = counts[e];
    const int m0 = blockIdx.y * BM;
    if (m0 >= Ne) return;
    const int n0 = blockIdx.x * BN;

    __shared__ __align__(16) char S[2 * HT];
    char* Sb0 = S;
    char* Sb1 = S + HT;

    const int tid = threadIdx.x, lane = tid & 63, wv = tid >> 6;
    const int* tl = tlist + e * T_TOK;

    // per-lane global pointers; source pre-swizzled (gl_lds writes linearly)
    const int rl = lane >> 3;                 // row within 8-row chunk (0..7)
    const int sl = (lane & 7) ^ rl;           // swizzled 16B slot
    const ushort* bp[CPW];
#pragma unroll
    for (int i = 0; i < CPW; ++i) {
        const int c = wv * CPW + i;
        if (c < ACH) {
            int slot = m0 + c * 8 + rl;
            if (slot > Ne - 1) slot = Ne - 1;
            bp[i] = A + (size_t)tl[slot] * KSTRIDE + sl * 8;
        } else {
            const int r = (c - ACH) * 8 + rl;
            bp[i] = W + ((size_t)e * NTOT + n0 + r) * KSTRIDE + sl * 8;
        }
    }

    f32x4 acc[MR][NR];
#pragma unroll
    for (int m = 0; m < MR; ++m)
#pragma unroll
        for (int n = 0; n < NR; ++n) acc[m][n] = (f32x4)0.f;

    const int wrow = (wv >> 1) * (BM / 2);    // 2x2 wave grid
    const int wcol = (wv & 1) * (BN / 2);

#define STAGE(T, BUF)                                                   \
    {                                                                   \
        _Pragma("unroll")                                               \
        for (int i = 0; i < CPW; ++i)                                   \
            gl_lds16(bp[i] + (T) * BK, (BUF) + (wv * CPW + i) * 1024);  \
    }

    STAGE(0, Sb0);
    STAGE(1, Sb1);

    for (int t = 0; t < NT; ++t) {
        char* curB = (t & 1) ? Sb1 : Sb0;
        if (t + 1 < NT) vm_wait<CPW>();       // tile t landed, t+1 in flight
        else            vm_wait<0>();         // tail: drain
        sbar();
#pragma unroll
        for (int ks = 0; ks < 2; ++ks) {
            const int kb = ks * 64 + (lane >> 4) * 16;
            bf16x8 af[MR], bfr[NR];
#pragma unroll
            for (int m = 0; m < MR; ++m) {
                const int r = wrow + m * 16 + (lane & 15);
                const int b = (r * 128 + kb) ^ ((r & 7) << 4);
                af[m] = *(const bf16x8*)(curB + b);
            }
#pragma unroll
            for (int n = 0; n < NR; ++n) {
                const int r = wcol + n * 16 + (lane & 15);
                const int b = (r * 128 + kb) ^ ((r & 7) << 4);
                bfr[n] = *(const bf16x8*)(curB + BM * 128 + b);
            }
#pragma unroll
            for (int m = 0; m < MR; ++m)
#pragma unroll
                for (int n = 0; n < NR; ++n)
                    acc[m][n] = __builtin_amdgcn_mfma_f32_16x16x32_bf16(
                        af[m], bfr[n], acc[m][n], 0, 0, 0);
        }
        sbar();                               // all waves done reading curB
        if (t + 2 < NT) STAGE(t + 2, curB);
    }
#undef STAGE

    // epilogue: C frag row=(lane>>4)*4+j, col=lane&15  [m89 layout]
    const int lr4 = (lane >> 4) * 4, lc = lane & 15;
#pragma unroll
    for (int m = 0; m < MR; ++m) {
        const int rbase = wrow + m * 16 + lr4;
#pragma unroll
        for (int j = 0; j < 4; ++j) {
            const int slot = m0 + rbase + j;
            if (slot >= Ne) continue;
            const int t = tl[slot];
            const float g = (MODE == 2) ? gates[t] : 0.f;
#pragma unroll
            for (int n = 0; n < NR; ++n) {
                float v = acc[m][n][j];
                const int c = n0 + wcol + n * 16 + lc;
                if (MODE == 1) {
                    float gv = 0.5f * v * (1.0f + erff(v * 0.70710678118654752f));
                    H[(size_t)t * NTOT + c] = f2bf(gv);
                } else {
                    Out[(size_t)t * NTOT + c] = v * g;
                }
            }
        }
    }
}

// ---------------- finalize: lb_loss, counts, avg gate, active --------------
__global__ __launch_bounds__(256) void finalize_kernel(
    const float* __restrict__ gates, const int* __restrict__ counts,
    float* __restrict__ tail)
{
    __shared__ float red[256];
    float s = 0.f;
    for (int i = threadIdx.x; i < T_TOK; i += 256) s += gates[i];
    red[threadIdx.x] = s;
    __syncthreads();
    for (int off = 128; off > 0; off >>= 1) {
        if (threadIdx.x < off) red[threadIdx.x] += red[threadIdx.x + off];
        __syncthreads();
    }
    if (threadIdx.x == 0) {
        float lb = 0.f; int active = 0;
#pragma unroll
        for (int e = 0; e < EXP; ++e) {
            float c = (float)counts[e];
            float d = c - 512.0f;
            lb += d * d;
            active += (counts[e] > 0) ? 1 : 0;
        }
        tail[0] = lb * (0.01f / 8.0f);
#pragma unroll
        for (int e = 0; e < EXP; ++e) tail[1 + e] = (float)counts[e];
        tail[9]  = red[0] / (float)T_TOK;
        tail[10] = (float)active;
    }
}

// ---------------- launch ---------------------------------------------------
extern "C" void kernel_launch(void* const* d_in, const int* in_sizes, int n_in,
                              void* d_out, int out_size, void* d_ws, size_t ws_size,
                              hipStream_t stream)
{
    const float* x  = (const float*)d_in[0];
    const float* Wr = (const float*)d_in[2];
    const float* W1 = (const float*)d_in[5];
    const float* W2 = (const float*)d_in[6];
    float* out = (float*)d_out;

    char* ws = (char*)d_ws;
    int*    counts = (int*)ws;                       // 256 B
    int*    tlist  = (int*)(ws + 256);               // 128 KiB
    float*  gates  = (float*)(ws + 131328);          // 16 KiB
    ushort* xb     = (ushort*)(ws + 147712);         // 6.29 MB
    ushort* h      = (ushort*)(ws + 6439168);        // 25.2 MB
    ushort* w1b    = (ushort*)(ws + 31604992);       // 37.75 MB
    const size_t OFF_W2B = 69353728ull;
    const bool fuse = ws_size >= OFF_W2B + 37748736ull;
    ushort* w2b = fuse ? (ushort*)(ws + OFF_W2B) : w1b;

    hipMemsetAsync(counts, 0, 256, stream);
    router_kernel<<<dim3(T_TOK / 4), dim3(256), 0, stream>>>(
        x, Wr, counts, tlist, gates, xb);

    if (fuse) {
        convboth_kernel<<<dim3(2304), dim3(256), 0, stream>>>(W1, w1b, W2, w2b);
    } else {
        convone_kernel<<<dim3(2304), dim3(256), 0, stream>>>(W1, w1b);
    }

    // GEMM1: 128x128 tile, 768 live blocks, 64 KB LDS -> 2 blk/CU
    moe_gemm<128, 128, FDIM, DDIM, 1>
        <<<dim3(FDIM / 128, T_TOK / 128, EXP), dim3(256), 0, stream>>>(
        xb, w1b, h, nullptr, counts, tlist, gates);

    if (!fuse) {  // sequential fallback: reuse w1b for W2
        convone_kernel<<<dim3(2304), dim3(256), 0, stream>>>(W2, w1b);
    }

    // GEMM2: 128x64 tile, K=3072 (NT=48), 384 live blocks, 48 KB LDS -> 3 blk/CU
    moe_gemm<128, 64, DDIM, FDIM, 2>
        <<<dim3(DDIM / 64, T_TOK / 128, EXP), dim3(256), 0, stream>>>(
        h, w2b, nullptr, out, counts, tlist, gates);

    finalize_kernel<<<dim3(1), dim3(256), 0, stream>>>(gates, counts, out + (size_t)T_TOK * DDIM);
}